// Round 14
// baseline (106.604 us; speedup 1.0000x reference)
//
#include <hip/hip_runtime.h>

typedef __attribute__((ext_vector_type(8))) _Float16 f16x8;  // 8 f16 in 4 VGPRs
typedef __attribute__((ext_vector_type(2))) __fp16 fp16x2r;  // cvt_pkrtz return type
typedef __attribute__((ext_vector_type(4))) float f32x4;
typedef __attribute__((ext_vector_type(2))) float f32x2;

#define BLK   256
#define NWAVE 4
#define NPT   16      // points per wave-tile
#define MAXB  2048

union F16U  { uint4 u; f16x8 v; };
union PairU { float4 f4; f32x2 p[2]; };   // view float4 as two aligned f32 pairs
union AccU  { f32x4 v; f32x2 p[2]; };     // view MFMA acc as two aligned pairs

// ---- packed dual-FP32 via native vector ops (compiler selects v_pk_*). ----
__device__ __forceinline__ f32x2 pk_fma(f32x2 a, f32x2 b, f32x2 c) {
    return __builtin_elementwise_fma(a, b, c);
}
__device__ __forceinline__ f32x2 pk_mul(f32x2 a, f32x2 b) { return a * b; }
__device__ __forceinline__ f32x2 pk_add(f32x2 a, f32x2 b) { return a + b; }

// Packed tanh pair: exp2/rcp ~1 ulp; trans ops scalar, VALU glue packed.
__device__ __forceinline__ f32x2 tanh2(f32x2 a, f32x2 cst2, f32x2 one2, f32x2 ntwo2) {
    f32x2 earg = pk_mul(a, cst2);
    f32x2 e;
    e.x = __builtin_amdgcn_exp2f(earg.x);
    e.y = __builtin_amdgcn_exp2f(earg.y);
    f32x2 ep1 = pk_add(e, one2);
    f32x2 r;
    r.x = __builtin_amdgcn_rcpf(ep1.x);
    r.y = __builtin_amdgcn_rcpf(ep1.y);
    return pk_fma(ntwo2, r, one2);     // 1 - 2/(e^2a+1)
}

// Two f32 -> packed f16x2 in one v_cvt_pkrtz_f16_f32.
__device__ __forceinline__ unsigned int pkh(float a, float b) {
    union { fp16x2r h; unsigned int u; } t;
    t.h = __builtin_amdgcn_cvt_pkrtz(a, b);
    return t.u;
}

__device__ __forceinline__ f16x8 pack8h(const float* v) {
    F16U r;
    r.u = make_uint4(pkh(v[0], v[1]), pkh(v[2], v[3]),
                     pkh(v[4], v[5]), pkh(v[6], v[7]));
    return r.v;
}

#define MFMA __builtin_amdgcn_mfma_f32_16x16x32_f16

// Round-14 = round-13 with ONE change: __launch_bounds__(256, 1).
// r13's VGPR_Count=48 << true live set (~110) proves the allocator parked the
// working set in AGPRs (heuristic chases occupancy), paying v_accvgpr copies
// on the critical path — the gap between ~400 counted issue-slots/tile and
// ~1500 measured. N=1 -> 256-reg budget, target occupancy 1 wave/EU -> no
// incentive to park; live set stays in arch VGPRs. Occupancy was proven a
// non-lever (r5/r7/r8 identical at 18-30%). Everything else byte-identical,
// so VGPR_Count is a clean go/no-go diagnostic for the parking theory.
__global__ __launch_bounds__(BLK, 1) void curl_mfma(
    const float* __restrict__ x,  const float* __restrict__ W1,
    const float* __restrict__ b1, const float* __restrict__ W2,
    const float* __restrict__ b2, const float* __restrict__ W3,
    float* __restrict__ out, int npts, int iters, int ntiles)
{
    // sA[(m*2+kc)*64 + lane]: packed f16 A fragment. Per-lane 16B -> conflict-free.
    __shared__ uint4  sA[8 * 64];     // 8 KiB
    // Pair tables, slot-permuted so the 4 simultaneous q-addresses are 16B apart.
    __shared__ float4 sW1xy[32], sW1zb[32];   // 1 KiB
    __shared__ float4 sLUTa[32], sLUTb[32];   // 1 KiB

    const int tid  = threadIdx.x;
    const int wv   = tid >> 6;
    const int lane = tid & 63;
    const int p    = lane & 15;   // point-in-tile == B col == D col
    const int q    = lane >> 4;   // k-group (kappa) and h-subgroup of D

    if (tid < 32) {
        // W1 pair tables: tid = qq*8 + kc*4 + u
        {
            const int qq = tid >> 3, kc = (tid >> 2) & 1, u = tid & 3;
            const int k0 = qq * 16 + kc * 8 + u * 2, k1 = k0 + 1;
            const int slot = ((kc * 4 + u) << 2) | qq;
            sW1xy[slot] = make_float4(W1[k0*3+0], W1[k1*3+0], W1[k0*3+1], W1[k1*3+1]);
            sW1zb[slot] = make_float4(W1[k0*3+2], W1[k1*3+2], b1[k0],     b1[k1]);
        }
        // LUT pair tables: tid = m*8 + qq*2 + rp
        {
            const int m = tid >> 3, qq = (tid >> 1) & 3, rp = tid & 1;
            const int h0 = m * 16 + qq * 4 + rp * 2, h1 = h0 + 1;
            sLUTa[tid] = make_float4(b2[h0], b2[h1], W3[h0], W3[h1]);
            sLUTb[tid] = make_float4(W3[64+h0], W3[64+h1], W3[128+h0], W3[128+h1]);
        }
    }

    // Wave wv builds the A fragments for m = wv (W2 row m*16+p, k = kappa(q,kc,j)).
    {
        const int m = wv;
#pragma unroll
        for (int kc = 0; kc < 2; ++kc) {
            const float* src = W2 + (m * 16 + p) * 64 + q * 16 + kc * 8;
            const float4 va = ((const float4*)src)[0];
            const float4 vb = ((const float4*)src)[1];
            const float vv[8] = {va.x, va.y, va.z, va.w, vb.x, vb.y, vb.z, vb.w};
            F16U uh; uh.v = pack8h(vv);
            sA[(m * 2 + kc) * 64 + lane] = uh.u;
        }
    }
    __syncthreads();   // tables ready; no barriers after this point

    // Loop-invariant packed constants.
    const f32x2 one2  = {1.0f, 1.0f};
    const f32x2 none2 = {-1.0f, -1.0f};
    const f32x2 ntwo2 = {-2.0f, -2.0f};
    const f32x2 cst2  = {2.8853900817779268f, 2.8853900817779268f};

    const int gw = blockIdx.x * NWAVE + wv;
    const int nw = gridDim.x * NWAVE;

    for (int it = 0; it < iters; ++it) {
        const int tile = gw + it * nw;
        if (tile >= ntiles) break;         // no barriers -> divergent exit is safe
        const int id = tile * NPT + p;

        float x0 = 0.f, x1 = 0.f, x2 = 0.f;
        if (id < npts) {
            x0 = x[id * 3 + 0];
            x1 = x[id * 3 + 1];
            x2 = x[id * 3 + 2];
        }
        const f32x2 x0_2 = {x0, x0}, x1_2 = {x1, x1}, x2_2 = {x2, x2};

        // ---- Layer 1 + g = D1*W1col, pair-packed; pack into f16 B fragments ----
        f16x8 Bf[4][2];                    // [type][kc] — 32 VGPRs
#pragma unroll
        for (int kc = 0; kc < 2; ++kc) {
            unsigned int wh[4], w0[4], w1[4], w2[4];
#pragma unroll
            for (int u = 0; u < 4; ++u) {
                PairU wxy, wzb;
                wxy.f4 = sW1xy[((kc * 4 + u) << 2) | q];
                wzb.f4 = sW1zb[((kc * 4 + u) << 2) | q];
                f32x2 a = pk_fma(wxy.p[0], x0_2, wzb.p[1]);   // W1x*x0 + b1
                a = pk_fma(wxy.p[1], x1_2, a);
                a = pk_fma(wzb.p[0], x2_2, a);
                const f32x2 th = tanh2(a, cst2, one2, ntwo2);
                const f32x2 t2 = pk_mul(th, th);
                const f32x2 d1 = pk_fma(t2, none2, one2);     // 1 - th^2
                const f32x2 g0 = pk_mul(d1, wxy.p[0]);
                const f32x2 g1 = pk_mul(d1, wxy.p[1]);
                const f32x2 g2 = pk_mul(d1, wzb.p[0]);
                wh[u] = pkh(th.x, th.y);
                w0[u] = pkh(g0.x, g0.y);
                w1[u] = pkh(g1.x, g1.y);
                w2[u] = pkh(g2.x, g2.y);
            }
            F16U t;
            t.u = make_uint4(wh[0], wh[1], wh[2], wh[3]); Bf[0][kc] = t.v;
            t.u = make_uint4(w0[0], w0[1], w0[2], w0[3]); Bf[1][kc] = t.v;
            t.u = make_uint4(w1[0], w1[1], w1[2], w1[3]); Bf[2][kc] = t.v;
            t.u = make_uint4(w2[0], w2[1], w2[2], w2[3]); Bf[3][kc] = t.v;
        }

        // ---- MFMA + pair-packed epilogue; curl via +/- accumulators ----
        f32x2 cp0 = {0.f,0.f}, cp1 = cp0, cp2 = cp0;
        f32x2 cn0 = cp0, cn1 = cp0, cn2 = cp0;
#pragma unroll 1
        for (int m = 0; m < 4; ++m) {
            F16U A0, A1;
            const uint4* pA = &sA[(m * 2) * 64 + lane];
            A0.u = pA[0];
            A1.u = pA[64];

            AccU a0, a1, a2, a3;
            a0.v = (f32x4){0.f,0.f,0.f,0.f}; a1.v = a0.v; a2.v = a0.v; a3.v = a0.v;
            a0.v = MFMA(A0.v, Bf[0][0], a0.v, 0, 0, 0);
            a1.v = MFMA(A0.v, Bf[1][0], a1.v, 0, 0, 0);
            a2.v = MFMA(A0.v, Bf[2][0], a2.v, 0, 0, 0);
            a3.v = MFMA(A0.v, Bf[3][0], a3.v, 0, 0, 0);
            a0.v = MFMA(A1.v, Bf[0][1], a0.v, 0, 0, 0);
            a1.v = MFMA(A1.v, Bf[1][1], a1.v, 0, 0, 0);
            a2.v = MFMA(A1.v, Bf[2][1], a2.v, 0, 0, 0);
            a3.v = MFMA(A1.v, Bf[3][1], a3.v, 0, 0, 0);

            // Epilogue pairs rp: h = m*16 + q*4 + {2rp, 2rp+1}
#pragma unroll
            for (int rp = 0; rp < 2; ++rp) {
                PairU la, lb;
                la.f4 = sLUTa[m * 8 + q * 2 + rp];
                lb.f4 = sLUTb[m * 8 + q * 2 + rp];
                const f32x2 s0 = pk_add(a0.p[rp], la.p[0]);
                const f32x2 th = tanh2(s0, cst2, one2, ntwo2);
                const f32x2 t2 = pk_mul(th, th);
                const f32x2 d2 = pk_fma(t2, none2, one2);
                const f32x2 e0 = pk_mul(la.p[1], d2);
                const f32x2 e1 = pk_mul(lb.p[0], d2);
                const f32x2 e2 = pk_mul(lb.p[1], d2);
                // c0 += e2*u1 - e1*u2 ; c1 += e0*u2 - e2*u0 ; c2 += e1*u0 - e0*u1
                cp0 = pk_fma(e2, a2.p[rp], cp0);  cn0 = pk_fma(e1, a3.p[rp], cn0);
                cp1 = pk_fma(e0, a3.p[rp], cp1);  cn1 = pk_fma(e2, a1.p[rp], cn1);
                cp2 = pk_fma(e1, a1.p[rp], cp2);  cn2 = pk_fma(e0, a2.p[rp], cn2);
            }
        }

        float c0 = (cp0.x - cn0.x) + (cp0.y - cn0.y);
        float c1 = (cp1.x - cn1.x) + (cp1.y - cn1.y);
        float c2 = (cp2.x - cn2.x) + (cp2.y - cn2.y);

        // Reduce partial curls over the 4 h-subgroups (q dimension).
        c0 += __shfl_xor(c0, 16); c0 += __shfl_xor(c0, 32);
        c1 += __shfl_xor(c1, 16); c1 += __shfl_xor(c1, 32);
        c2 += __shfl_xor(c2, 16); c2 += __shfl_xor(c2, 32);

        // Coalesced store: lane (p,q<3) writes component q of point p.
        if (q < 3 && id < npts) {
            const float cv = (q == 0) ? c0 : ((q == 1) ? c1 : c2);
            out[tile * (NPT * 3) + p * 3 + q] = cv;
        }
    }
}

extern "C" void kernel_launch(void* const* d_in, const int* in_sizes, int n_in,
                              void* d_out, int out_size, void* d_ws, size_t ws_size,
                              hipStream_t stream) {
    const float* x  = (const float*)d_in[0];
    const float* W1 = (const float*)d_in[1];
    const float* b1 = (const float*)d_in[2];
    const float* W2 = (const float*)d_in[3];
    const float* b2 = (const float*)d_in[4];
    const float* W3 = (const float*)d_in[5];
    // d_in[6] (b3) unused: it cancels in the Jacobian.
    float* out = (float*)d_out;

    const int npts   = in_sizes[0] / 3;
    const int ntiles = (npts + NPT - 1) / NPT;
    int blocks = (ntiles + NWAVE - 1) / NWAVE;
    if (blocks > MAXB) blocks = MAXB;
    const int nw    = blocks * NWAVE;
    const int iters = (ntiles + nw - 1) / nw;

    hipLaunchKernelGGL(curl_mfma, dim3(blocks), dim3(BLK), 0, stream,
                       x, W1, b1, W2, b2, W3, out, npts, iters, ntiles);
}

// Round 16
// 104.038 us; speedup vs baseline: 1.0247x; 1.0247x over previous
//
#include <hip/hip_runtime.h>

typedef __attribute__((ext_vector_type(8))) _Float16 f16x8;  // 8 f16 in 4 VGPRs
typedef __attribute__((ext_vector_type(2))) __fp16 fp16x2r;  // cvt_pkrtz return type
typedef __attribute__((ext_vector_type(4))) float f32x4;
typedef __attribute__((ext_vector_type(2))) float f32x2;

#define BLK   256
#define NWAVE 4
#define NPT   16      // points per wave-tile
#define MAXB  2048

union F16U  { uint4 u; f16x8 v; };
union PairU { float4 f4; f32x2 p[2]; };   // view float4 as two aligned f32 pairs
union AccU  { f32x4 v; f32x2 p[2]; };     // view MFMA acc as two aligned pairs

// ---- packed dual-FP32 via native vector ops (compiler selects v_pk_*). ----
__device__ __forceinline__ f32x2 pk_fma(f32x2 a, f32x2 b, f32x2 c) {
    return __builtin_elementwise_fma(a, b, c);
}
__device__ __forceinline__ f32x2 pk_mul(f32x2 a, f32x2 b) { return a * b; }
__device__ __forceinline__ f32x2 pk_add(f32x2 a, f32x2 b) { return a + b; }

// Packed tanh pair: exp2/rcp ~1 ulp; trans ops scalar, VALU glue packed.
__device__ __forceinline__ f32x2 tanh2(f32x2 a, f32x2 cst2, f32x2 one2, f32x2 ntwo2) {
    f32x2 earg = pk_mul(a, cst2);
    f32x2 e;
    e.x = __builtin_amdgcn_exp2f(earg.x);
    e.y = __builtin_amdgcn_exp2f(earg.y);
    f32x2 ep1 = pk_add(e, one2);
    f32x2 r;
    r.x = __builtin_amdgcn_rcpf(ep1.x);
    r.y = __builtin_amdgcn_rcpf(ep1.y);
    return pk_fma(ntwo2, r, one2);     // 1 - 2/(e^2a+1)
}

// Two f32 -> packed f16x2 in one v_cvt_pkrtz_f16_f32.
__device__ __forceinline__ unsigned int pkh(float a, float b) {
    union { fp16x2r h; unsigned int u; } t;
    t.h = __builtin_amdgcn_cvt_pkrtz(a, b);
    return t.u;
}

__device__ __forceinline__ f16x8 pack8h(const float* v) {
    F16U r;
    r.u = make_uint4(pkh(v[0], v[1]), pkh(v[2], v[3]),
                     pkh(v[4], v[5]), pkh(v[6], v[7]));
    return r.v;
}

#define MFMA __builtin_amdgcn_mfma_f32_16x16x32_f16

// Round-16 = round-15 resubmitted (GPU acquisition timeout; never ran).
// = round-13 (best, 45.0us) + ONE change: the m-loop is FULLY UNROLLED
// (was unroll 1). Model from r13/r14 counters: trans ops (exp/rcp) execute at
// ~16 cyc/wave-op on the VALU pipe (64/tile ~= 1024 cyc, matching the VALUBusy
// residual), and the serial per-m epilogue chains leave ~1k cyc/tile of
// dependency stall at ~3 waves/SIMD. Unrolling lets the scheduler overlap
// m+1's MFMA/LDS/trans with m's chains (ILP, the one untried lever — occupancy
// was proven a non-lever in r5/r7/r8, and lb(256,1) regressed in r14).
// With f16, A is 8 regs/m -> 32 unrolled; live set ~160 fits the 256 budget.
// kappa(q,kc,j)=q*16+kc*8+j shared by A and B cancels in the contraction.
// C/D: col=lane&15=p, row=(lane>>4)*4+reg -> h=m*16+q*4+r; epilogue lane-local.
__global__ __launch_bounds__(BLK, 2) void curl_mfma(
    const float* __restrict__ x,  const float* __restrict__ W1,
    const float* __restrict__ b1, const float* __restrict__ W2,
    const float* __restrict__ b2, const float* __restrict__ W3,
    float* __restrict__ out, int npts, int iters, int ntiles)
{
    // sA[(m*2+kc)*64 + lane]: packed f16 A fragment. Per-lane 16B -> conflict-free.
    __shared__ uint4  sA[8 * 64];     // 8 KiB
    // Pair tables, slot-permuted so the 4 simultaneous q-addresses are 16B apart.
    __shared__ float4 sW1xy[32], sW1zb[32];   // 1 KiB
    __shared__ float4 sLUTa[32], sLUTb[32];   // 1 KiB

    const int tid  = threadIdx.x;
    const int wv   = tid >> 6;
    const int lane = tid & 63;
    const int p    = lane & 15;   // point-in-tile == B col == D col
    const int q    = lane >> 4;   // k-group (kappa) and h-subgroup of D

    if (tid < 32) {
        // W1 pair tables: tid = qq*8 + kc*4 + u
        {
            const int qq = tid >> 3, kc = (tid >> 2) & 1, u = tid & 3;
            const int k0 = qq * 16 + kc * 8 + u * 2, k1 = k0 + 1;
            const int slot = ((kc * 4 + u) << 2) | qq;
            sW1xy[slot] = make_float4(W1[k0*3+0], W1[k1*3+0], W1[k0*3+1], W1[k1*3+1]);
            sW1zb[slot] = make_float4(W1[k0*3+2], W1[k1*3+2], b1[k0],     b1[k1]);
        }
        // LUT pair tables: tid = m*8 + qq*2 + rp
        {
            const int m = tid >> 3, qq = (tid >> 1) & 3, rp = tid & 1;
            const int h0 = m * 16 + qq * 4 + rp * 2, h1 = h0 + 1;
            sLUTa[tid] = make_float4(b2[h0], b2[h1], W3[h0], W3[h1]);
            sLUTb[tid] = make_float4(W3[64+h0], W3[64+h1], W3[128+h0], W3[128+h1]);
        }
    }

    // Wave wv builds the A fragments for m = wv (W2 row m*16+p, k = kappa(q,kc,j)).
    {
        const int m = wv;
#pragma unroll
        for (int kc = 0; kc < 2; ++kc) {
            const float* src = W2 + (m * 16 + p) * 64 + q * 16 + kc * 8;
            const float4 va = ((const float4*)src)[0];
            const float4 vb = ((const float4*)src)[1];
            const float vv[8] = {va.x, va.y, va.z, va.w, vb.x, vb.y, vb.z, vb.w};
            F16U uh; uh.v = pack8h(vv);
            sA[(m * 2 + kc) * 64 + lane] = uh.u;
        }
    }
    __syncthreads();   // tables ready; no barriers after this point

    // Loop-invariant packed constants.
    const f32x2 one2  = {1.0f, 1.0f};
    const f32x2 none2 = {-1.0f, -1.0f};
    const f32x2 ntwo2 = {-2.0f, -2.0f};
    const f32x2 cst2  = {2.8853900817779268f, 2.8853900817779268f};

    const int gw = blockIdx.x * NWAVE + wv;
    const int nw = gridDim.x * NWAVE;

    for (int it = 0; it < iters; ++it) {
        const int tile = gw + it * nw;
        if (tile >= ntiles) break;         // no barriers -> divergent exit is safe
        const int id = tile * NPT + p;

        float x0 = 0.f, x1 = 0.f, x2 = 0.f;
        if (id < npts) {
            x0 = x[id * 3 + 0];
            x1 = x[id * 3 + 1];
            x2 = x[id * 3 + 2];
        }
        const f32x2 x0_2 = {x0, x0}, x1_2 = {x1, x1}, x2_2 = {x2, x2};

        // ---- Layer 1 + g = D1*W1col, pair-packed; pack into f16 B fragments ----
        f16x8 Bf[4][2];                    // [type][kc] — 32 VGPRs
#pragma unroll
        for (int kc = 0; kc < 2; ++kc) {
            unsigned int wh[4], w0[4], w1[4], w2[4];
#pragma unroll
            for (int u = 0; u < 4; ++u) {
                PairU wxy, wzb;
                wxy.f4 = sW1xy[((kc * 4 + u) << 2) | q];
                wzb.f4 = sW1zb[((kc * 4 + u) << 2) | q];
                f32x2 a = pk_fma(wxy.p[0], x0_2, wzb.p[1]);   // W1x*x0 + b1
                a = pk_fma(wxy.p[1], x1_2, a);
                a = pk_fma(wzb.p[0], x2_2, a);
                const f32x2 th = tanh2(a, cst2, one2, ntwo2);
                const f32x2 t2 = pk_mul(th, th);
                const f32x2 d1 = pk_fma(t2, none2, one2);     // 1 - th^2
                const f32x2 g0 = pk_mul(d1, wxy.p[0]);
                const f32x2 g1 = pk_mul(d1, wxy.p[1]);
                const f32x2 g2 = pk_mul(d1, wzb.p[0]);
                wh[u] = pkh(th.x, th.y);
                w0[u] = pkh(g0.x, g0.y);
                w1[u] = pkh(g1.x, g1.y);
                w2[u] = pkh(g2.x, g2.y);
            }
            F16U t;
            t.u = make_uint4(wh[0], wh[1], wh[2], wh[3]); Bf[0][kc] = t.v;
            t.u = make_uint4(w0[0], w0[1], w0[2], w0[3]); Bf[1][kc] = t.v;
            t.u = make_uint4(w1[0], w1[1], w1[2], w1[3]); Bf[2][kc] = t.v;
            t.u = make_uint4(w2[0], w2[1], w2[2], w2[3]); Bf[3][kc] = t.v;
        }

        // ---- MFMA + pair-packed epilogue; curl via +/- accumulators ----
        // FULLY UNROLLED over m: scheduler may overlap m+1's MFMA/LDS with
        // m's trans chains.
        f32x2 cp0 = {0.f,0.f}, cp1 = cp0, cp2 = cp0;
        f32x2 cn0 = cp0, cn1 = cp0, cn2 = cp0;
#pragma unroll
        for (int m = 0; m < 4; ++m) {
            F16U A0, A1;
            const uint4* pA = &sA[(m * 2) * 64 + lane];
            A0.u = pA[0];
            A1.u = pA[64];

            AccU a0, a1, a2, a3;
            a0.v = (f32x4){0.f,0.f,0.f,0.f}; a1.v = a0.v; a2.v = a0.v; a3.v = a0.v;
            a0.v = MFMA(A0.v, Bf[0][0], a0.v, 0, 0, 0);
            a1.v = MFMA(A0.v, Bf[1][0], a1.v, 0, 0, 0);
            a2.v = MFMA(A0.v, Bf[2][0], a2.v, 0, 0, 0);
            a3.v = MFMA(A0.v, Bf[3][0], a3.v, 0, 0, 0);
            a0.v = MFMA(A1.v, Bf[0][1], a0.v, 0, 0, 0);
            a1.v = MFMA(A1.v, Bf[1][1], a1.v, 0, 0, 0);
            a2.v = MFMA(A1.v, Bf[2][1], a2.v, 0, 0, 0);
            a3.v = MFMA(A1.v, Bf[3][1], a3.v, 0, 0, 0);

            // Epilogue pairs rp: h = m*16 + q*4 + {2rp, 2rp+1}
#pragma unroll
            for (int rp = 0; rp < 2; ++rp) {
                PairU la, lb;
                la.f4 = sLUTa[m * 8 + q * 2 + rp];
                lb.f4 = sLUTb[m * 8 + q * 2 + rp];
                const f32x2 s0 = pk_add(a0.p[rp], la.p[0]);
                const f32x2 th = tanh2(s0, cst2, one2, ntwo2);
                const f32x2 t2 = pk_mul(th, th);
                const f32x2 d2 = pk_fma(t2, none2, one2);
                const f32x2 e0 = pk_mul(la.p[1], d2);
                const f32x2 e1 = pk_mul(lb.p[0], d2);
                const f32x2 e2 = pk_mul(lb.p[1], d2);
                // c0 += e2*u1 - e1*u2 ; c1 += e0*u2 - e2*u0 ; c2 += e1*u0 - e0*u1
                cp0 = pk_fma(e2, a2.p[rp], cp0);  cn0 = pk_fma(e1, a3.p[rp], cn0);
                cp1 = pk_fma(e0, a3.p[rp], cp1);  cn1 = pk_fma(e2, a1.p[rp], cn1);
                cp2 = pk_fma(e1, a1.p[rp], cp2);  cn2 = pk_fma(e0, a2.p[rp], cn2);
            }
        }

        float c0 = (cp0.x - cn0.x) + (cp0.y - cn0.y);
        float c1 = (cp1.x - cn1.x) + (cp1.y - cn1.y);
        float c2 = (cp2.x - cn2.x) + (cp2.y - cn2.y);

        // Reduce partial curls over the 4 h-subgroups (q dimension).
        c0 += __shfl_xor(c0, 16); c0 += __shfl_xor(c0, 32);
        c1 += __shfl_xor(c1, 16); c1 += __shfl_xor(c1, 32);
        c2 += __shfl_xor(c2, 16); c2 += __shfl_xor(c2, 32);

        // Coalesced store: lane (p,q<3) writes component q of point p.
        if (q < 3 && id < npts) {
            const float cv = (q == 0) ? c0 : ((q == 1) ? c1 : c2);
            out[tile * (NPT * 3) + p * 3 + q] = cv;
        }
    }
}

extern "C" void kernel_launch(void* const* d_in, const int* in_sizes, int n_in,
                              void* d_out, int out_size, void* d_ws, size_t ws_size,
                              hipStream_t stream) {
    const float* x  = (const float*)d_in[0];
    const float* W1 = (const float*)d_in[1];
    const float* b1 = (const float*)d_in[2];
    const float* W2 = (const float*)d_in[3];
    const float* b2 = (const float*)d_in[4];
    const float* W3 = (const float*)d_in[5];
    // d_in[6] (b3) unused: it cancels in the Jacobian.
    float* out = (float*)d_out;

    const int npts   = in_sizes[0] / 3;
    const int ntiles = (npts + NPT - 1) / NPT;
    int blocks = (ntiles + NWAVE - 1) / NWAVE;
    if (blocks > MAXB) blocks = MAXB;
    const int nw    = blocks * NWAVE;
    const int iters = (ntiles + nw - 1) / nw;

    hipLaunchKernelGGL(curl_mfma, dim3(blocks), dim3(BLK), 0, stream,
                       x, W1, b1, W2, b2, W3, out, npts, iters, ntiles);
}